// Round 2
// 487.786 us; speedup vs baseline: 1.0872x; 1.0872x over previous
//
#include <hip/hip_runtime.h>

// Causal per-channel FIR via FFT (fft_size=16384) as packed 8192-pt complex
// FFTs. B=8, N=8192, D=512. Round 5 (= R4 with the PQ OOB-write bug fixed):
//  - all complex math on ext_vector float2 (v2f) to trigger v_pk_*_f32 (VOP3P)
//  - twiddles from precomputed __device__ tables (double-precision init kernel)
//  - spec multiply fused algebraically: Z'k = al*Zk + i*(R*conj(Zm)),
//    Z'm = conj(Dt)*Zm + i*conj(R*Zk), al=P+Q, R=P*u1-Q*u2, Dt=P*u3+Q*u4,
//    from per-(d,k) (P,Q) float4 rows (k in [0,4096] ONLY — mirror bins are
//    never read; R4 wrongly wrote them past the 4097 stride, corrupting
//    neighbor rows) + d-independent u/h tables
//  - g_h: double-accurate ((1-s)/2,(1+s)/2) to avoid 1-s cancellation near
//    k=4096 (u3=(1+s)/(1-s) reaches 2.7e7 there)
//  - XCD-aware block swizzle in k2 so all 8 b-blocks of one d share an L2

typedef float v2f __attribute__((ext_vector_type(2)));

#define PQ_STRIDE 4097
constexpr double PI_D = 3.14159265358979323846;

// ---- static device tables (input-independent, filled by k_init) ----
__device__ v2f    g_twA[15][512];  // e^{-i pi * tid * (j+1) / 4096}
__device__ v2f    g_twB[15][32];   // e^{-i pi * m2 * (j+1) / 256}
__device__ v2f    g_w81[4096];     // (cos, sin)(pi k / 8192), k in [0,4096)
__device__ v2f    g_h[4096];       // ((1-s)/2, (1+s)/2) double-accurate
__device__ float4 g_u[4097];       // (c/(1-s), c/(1+s), (1+s)/(1-s), (1-s)/(1+s))

__device__ __forceinline__ v2f mkv2(float x, float y) { v2f r; r.x = x; r.y = y; return r; }
// a*b  (complex)
__device__ __forceinline__ v2f cmul(v2f a, v2f b)  { return mkv2(a.x, a.x) * b + mkv2(-a.y, a.y) * b.yx; }
// a*conj(b)
__device__ __forceinline__ v2f cmulc(v2f a, v2f b) { return mkv2(a.x, -a.x) * b + mkv2(a.y, a.y) * b.yx; }
// conj(a)*b
__device__ __forceinline__ v2f cmulcA(v2f a, v2f b){ return mkv2(a.x, a.x) * b + mkv2(a.y, -a.y) * b.yx; }

// FFT16 leaves output X[k] in v[SLOT(k)]
#define SLOT(k) ((((k) & 3) << 2) | ((k) >> 2))

// LDS layouts (8B-element units, all within [0,8192)) — unchanged from R3.
__device__ __forceinline__ int addr1(int n2, int k1) {            // A[k1, n2]
    return (n2 << 4) | ((k1 + n2) & 15);
}
__device__ __forceinline__ int addr2(int r, int m2) {             // B[r=(k1*16+q1), m2]
    return (r << 5) | ((m2 + 2 * r) & 31);
}
__device__ __forceinline__ int addr3(int k) {                     // X[k], k natural bin
    int lo = (k + 2 * (k >> 4) + (k >> 8) + (k >> 12)) & 15;
    return (k & ~15) | lo;
}

// radix-4 butterfly. SGN=-1 forward, +1 inverse.
template <int SGN>
__device__ __forceinline__ void fft4(v2f& a, v2f& b, v2f& c, v2f& d) {
    v2f A0 = a + c, A1 = a - c, A2 = b + d, A3 = b - d;
    v2f T = (SGN < 0) ? mkv2(A3.y, -A3.x) : mkv2(-A3.y, A3.x);
    a = A0 + A2; b = A1 + T; c = A0 - A2; d = A1 - T;
}

template <int SGN>
__device__ __forceinline__ void fft16_tail(v2f* v) {
    const float C1 = 0.9238795325112867f, S1 = 0.3826834323650898f, R2 = 0.7071067811865476f;
    v[5]  = cmul(v[5],  mkv2(C1, SGN < 0 ? -S1 : S1));
    v[6]  = cmul(v[6],  mkv2(R2, SGN < 0 ? -R2 : R2));
    v[7]  = cmul(v[7],  mkv2(S1, SGN < 0 ? -C1 : C1));
    v[9]  = cmul(v[9],  mkv2(R2, SGN < 0 ? -R2 : R2));
    v[10] = (SGN < 0) ? mkv2(v[10].y, -v[10].x) : mkv2(-v[10].y, v[10].x);
    v[11] = cmul(v[11], mkv2(-R2, SGN < 0 ? -R2 : R2));
    v[13] = cmul(v[13], mkv2(S1, SGN < 0 ? -C1 : C1));
    v[14] = cmul(v[14], mkv2(-R2, SGN < 0 ? -R2 : R2));
    v[15] = cmul(v[15], mkv2(-C1, SGN < 0 ? S1 : -S1));
    fft4<SGN>(v[0], v[1], v[2], v[3]);
    fft4<SGN>(v[4], v[5], v[6], v[7]);
    fft4<SGN>(v[8], v[9], v[10], v[11]);
    fft4<SGN>(v[12], v[13], v[14], v[15]);
}
template <int SGN>
__device__ __forceinline__ void fft16(v2f* v) {   // natural in, X[k] at SLOT(k)
    fft4<SGN>(v[0], v[4], v[8], v[12]);
    fft4<SGN>(v[1], v[5], v[9], v[13]);
    fft4<SGN>(v[2], v[6], v[10], v[14]);
    fft4<SGN>(v[3], v[7], v[11], v[15]);
    fft16_tail<SGN>(v);
}
template <int SGN>
__device__ __forceinline__ void fft16_half(v2f* v) {  // v[0..7] in, upper half = 0
    #pragma unroll
    for (int j = 0; j < 4; ++j) {
        v2f a = v[j], b = v[j + 4];
        v2f T = (SGN < 0) ? mkv2(b.y, -b.x) : mkv2(-b.y, b.x);
        v[j] = a + b; v[j + 4] = a + T;
        v[j + 8] = a - b; v[j + 12] = a - T;
    }
    fft16_tail<SGN>(v);
}

__device__ __forceinline__ v2f shflx1(v2f v) {
    return mkv2(__shfl_xor(v.x, 1), __shfl_xor(v.y, 1));
}

#define W32_TABLES \
    constexpr float WC[16] = {1.f, 0.98078528f, 0.92387953f, 0.83146961f, 0.70710678f, \
        0.55557023f, 0.38268343f, 0.19509032f, 0.f, -0.19509032f, -0.38268343f, \
        -0.55557023f, -0.70710678f, -0.83146961f, -0.92387953f, -0.98078528f}; \
    constexpr float WS[16] = {0.f, 0.19509032f, 0.38268343f, 0.55557023f, 0.70710678f, \
        0.83146961f, 0.92387953f, 0.98078528f, 1.f, 0.98078528f, 0.92387953f, \
        0.83146961f, 0.70710678f, 0.55557023f, 0.38268343f, 0.19509032f};

// Forward levels 2+3: LDS1 (A[k1,n2] synced) -> ... -> LDS3 (X[k] at addr3), synced.
__device__ __forceinline__ void fwd_L2_L3(v2f* sbuf, int tid) {
    {   // L2: 16-pt FFT over m1 for each (k1, m2), twiddle from g_twB
        int k1 = tid >> 5, m2 = tid & 31;
        v2f w[15];
        #pragma unroll
        for (int j = 0; j < 15; ++j) w[j] = g_twB[j][m2];
        v2f u[16];
        #pragma unroll
        for (int m1 = 0; m1 < 16; ++m1) u[m1] = sbuf[addr1(32 * m1 + m2, k1)];
        __syncthreads();
        fft16<-1>(u);
        #pragma unroll
        for (int k = 1; k < 16; ++k) u[SLOT(k)] = cmul(u[SLOT(k)], w[k - 1]);
        #pragma unroll
        for (int q1 = 0; q1 < 16; ++q1) sbuf[addr2(k1 * 16 + q1, m2)] = u[SLOT(q1)];
        __syncthreads();
    }
    {   // L3: 32-pt FFT over m2 for each (k1,q1): paired threads, shfl combine
        int k1 = tid >> 5, q1 = (tid >> 1) & 15, half = tid & 1;
        v2f e[16];
        #pragma unroll
        for (int j = 0; j < 16; ++j) e[j] = sbuf[addr2(k1 * 16 + q1, 2 * j + half)];
        __syncthreads();
        fft16<-1>(e);
        W32_TABLES
        #pragma unroll
        for (int q = 0; q < 16; ++q) {
            v2f mine = e[SLOT(q)];
            v2f othr = shflx1(mine);
            v2f Eq = half ? othr : mine;
            v2f Oq = half ? mine : othr;
            v2f WO = cmul(mkv2(WC[q], -WS[q]), Oq);
            v2f X = half ? Eq - WO : Eq + WO;
            int k = k1 + 16 * q1 + 256 * (q + 16 * half);
            sbuf[addr3(k)] = X;
        }
        __syncthreads();
    }
}

// Inverse levels 3+2: LDS3 (Y[k] at addr3, synced) -> ... -> LDS1 (A'[k1,n2]), synced.
__device__ __forceinline__ void inv_L3_L2(v2f* sbuf, int tid) {
    {   // inv L3
        int k1 = tid >> 5, q1 = (tid >> 1) & 15, half = tid & 1;
        v2f t[16];
        #pragma unroll
        for (int q = 0; q < 16; ++q)
            t[q] = sbuf[addr3(k1 + 16 * q1 + 256 * (q + 16 * half))];
        __syncthreads();
        W32_TABLES
        #pragma unroll
        for (int q = 0; q < 16; ++q) {
            v2f othr = shflx1(t[q]);
            if (half) t[q] = cmul(mkv2(WC[q], WS[q]), othr - t[q]);
            else      t[q] = t[q] + othr;
        }
        fft16<1>(t);
        #pragma unroll
        for (int j = 0; j < 16; ++j) sbuf[addr2(k1 * 16 + q1, 2 * j + half)] = t[SLOT(j)];
        __syncthreads();
    }
    {   // inv L2: twiddle = conj(g_twB) applied to inputs (natural index)
        int k1 = tid >> 5, m2 = tid & 31;
        v2f w[15];
        #pragma unroll
        for (int j = 0; j < 15; ++j) w[j] = g_twB[j][m2];
        v2f u[16];
        #pragma unroll
        for (int q1 = 0; q1 < 16; ++q1) u[q1] = sbuf[addr2(k1 * 16 + q1, m2)];
        __syncthreads();
        #pragma unroll
        for (int k = 1; k < 16; ++k) u[k] = cmulc(u[k], w[k - 1]);
        fft16<1>(u);
        #pragma unroll
        for (int m1 = 0; m1 < 16; ++m1) sbuf[addr1(32 * m1 + m2, k1)] = u[SLOT(m1)];
        __syncthreads();
    }
}

// Inverse level 1: LDS1 -> registers, y[n1] at v[SLOT(n1)] (unnormalized).
__device__ __forceinline__ void inv_L1(const v2f* sbuf, int tid, v2f* v) {
    v2f w[15];
    #pragma unroll
    for (int j = 0; j < 15; ++j) w[j] = g_twA[j][tid];
    #pragma unroll
    for (int k1 = 0; k1 < 16; ++k1) v[k1] = sbuf[addr1(tid, k1)];
    #pragma unroll
    for (int k = 1; k < 16; ++k) v[k] = cmulc(v[k], w[k - 1]);
    fft16<1>(v);
}

// Linear interp of coeffs (512 -> 8192, half-pixel), a[0]=dc.
__device__ __forceinline__ float aval(const float* C, float dcv, int idx) {
    if (idx == 0) return dcv;
    int j = idx - 1;
    float src = ((float)j + 0.5f) * 0.0625f - 0.5f;
    src = fminf(fmaxf(src, 0.0f), 511.0f);
    int lo = (int)floorf(src);
    int hi = min(lo + 1, 511);
    float w = src - (float)lo;
    return C[lo] * (1.0f - w) + C[hi] * w;
}

// ---- fused packed-domain spectrum multiply -------------------------------
// Z'k = al*Zk + i*(R*conj(Zm));  Z'm = conj(Dt)*Zm + i*conj(R*Zk)
// with al = P+Q, R = u1*P - u2*Q (beta = i*R), Dt = u3*P + u4*Q (delta=conj(Dt)).
__device__ __forceinline__ void spec_single(v2f* sbuf, const float4* PQd, int k) {
    float4 uu = g_u[k];
    float4 pq = PQd[k];
    v2f P = mkv2(pq.x, pq.y), Q = mkv2(pq.z, pq.w);
    v2f al = P + Q;
    v2f R  = P * uu.x - Q * uu.y;
    int a = addr3(k);
    v2f Z = sbuf[a];
    v2f W = cmulc(R, Z);
    sbuf[a] = cmul(al, Z) + mkv2(-W.y, W.x);
}
__device__ __forceinline__ void spec_pair(v2f* sbuf, const float4* PQd, int k) {
    int m = 8192 - k;
    float4 uu = g_u[k];
    float4 pq = PQd[k];
    v2f P = mkv2(pq.x, pq.y), Q = mkv2(pq.z, pq.w);
    int ak = addr3(k), am = addr3(m);
    v2f Zk = sbuf[ak], Zm = sbuf[am];
    v2f al = P + Q;
    v2f R  = P * uu.x - Q * uu.y;
    v2f Dt = P * uu.z + Q * uu.w;
    v2f W = cmulc(R, Zm);            // R * conj(Zm)
    v2f V = cmul(R, Zk);             // R * Zk
    sbuf[ak] = cmul(al, Zk) + mkv2(-W.y, W.x);   // + i*W
    sbuf[am] = cmulcA(Dt, Zm) + V.yx;            // conj(Dt)*Zm + i*conj(V)
}

// ---- table init (input-independent, double precision) --------------------
__global__ void k_init() {
    int t = blockIdx.x * 512 + threadIdx.x;
    if (t < 4096) {
        double th = (PI_D / 8192.0) * (double)t;
        double s = sin(th), c = cos(th);
        g_w81[t] = mkv2((float)c, (float)s);
        g_h[t]   = mkv2((float)(0.5 * (1.0 - s)), (float)(0.5 * (1.0 + s)));
    }
    if (t <= 4096) {
        if (t == 4096) {
            g_u[t] = make_float4(0.f, 0.f, 0.f, 0.f);
        } else {
            double th = (PI_D / 8192.0) * (double)t;
            double s = sin(th), c = cos(th);
            g_u[t] = make_float4((float)(c / (1.0 - s)), (float)(c / (1.0 + s)),
                                 (float)((1.0 + s) / (1.0 - s)), (float)((1.0 - s) / (1.0 + s)));
        }
    }
    if (t < 7680) {
        int j = t >> 9, tt = t & 511;
        double th = -(PI_D / 4096.0) * (double)(tt * (j + 1));
        g_twA[j][tt] = mkv2((float)cos(th), (float)sin(th));
    }
    if (t < 480) {
        int j = t >> 5, m2 = t & 31;
        double th = -(PI_D / 256.0) * (double)(m2 * (j + 1));
        g_twB[j][m2] = mkv2((float)cos(th), (float)sin(th));
    }
}

// Fused: blocks [0,512) build PQ tables; blocks [512, 512+8192) transpose/pack x.
__global__ __launch_bounds__(512, 4) void k01(const float* __restrict__ x,
                                              const float* __restrict__ coeffs,
                                              const float* __restrict__ dc,
                                              float4* __restrict__ PQ,
                                              v2f* __restrict__ zin) {
    __shared__ v2f sbuf[8192];
    int tid = threadIdx.x;
    if (blockIdx.x < 512) {
        int d = blockIdx.x;
        const float* C = coeffs + d * 512;
        float dcv = dc[d];
        // Z_A[k] = Ae + i*Ao*e^{+i pi k/M}  (packed-irfft spectrum), into LDS3
        #pragma unroll
        for (int tt = 0; tt < 16; ++tt) {
            int k = tid + (tt << 9);
            float ak = aval(C, dcv, k);
            float am = aval(C, dcv, 8192 - k);
            float Ae = 0.5f * (ak + am), Ao = 0.5f * (ak - am);
            float sn, cs;
            if (tt < 8) { v2f w = g_w81[k];        cs = w.x;  sn = w.y; }
            else        { v2f w = g_w81[k - 4096]; cs = -w.y; sn = w.x; }
            sbuf[addr3(k)] = mkv2(Ae - Ao * sn, Ao * cs);
        }
        __syncthreads();
        inv_L3_L2(sbuf, tid);
        v2f v[16];
        inv_L1(sbuf, tid, v);          // packed time, x8192 scale
        // causal Hilbert window + renormalize; reorder to natural n1
        v2f u[16];
        #pragma unroll
        for (int n1 = 0; n1 < 16; ++n1) {
            v2f z = v[SLOT(n1)];
            int n = (n1 << 9) + tid;
            float te = z.x * (1.0f / 8192.0f);
            float to = z.y * (1.0f / 8192.0f);
            int m0 = 2 * n;
            float he = (m0 == 0) ? te : ((m0 < 8192) ? 2.0f * te : ((m0 == 8192) ? te : 0.0f));
            float ho = (m0 + 1 < 8192) ? 2.0f * to : 0.0f;
            u[n1] = mkv2(he, ho);
        }
        // forward L1 (full): same-row rewrite of LDS1, no barrier needed before
        fft16<-1>(u);
        v2f wA[15];
        #pragma unroll
        for (int j = 0; j < 15; ++j) wA[j] = g_twA[j][tid];
        #pragma unroll
        for (int k = 1; k < 16; ++k) u[SLOT(k)] = cmul(u[SLOT(k)], wA[k - 1]);
        #pragma unroll
        for (int k1 = 0; k1 < 16; ++k1) sbuf[addr1(tid, k1)] = u[SLOT(k1)];
        __syncthreads();
        fwd_L2_L3(sbuf, tid);
        // unpack packed-real FFT -> (P,Q) table rows, bins k in [0,4096] ONLY
        // (mirror bins are never read by k2 — and writing them would overrun
        // the 4097-stride row: that was R4's bug)
        float4* PQd = PQ + (size_t)d * PQ_STRIDE;
        const float scale = 1.0f / 8192.0f;
        #pragma unroll
        for (int tt = 0; tt < 8; ++tt) {
            int k = tid + (tt << 9);
            if (k == 0) {
                v2f Z0 = sbuf[addr3(0)];
                float S0 = (Z0.x + Z0.y) * scale;   // real
                float SM = (Z0.x - Z0.y) * scale;   // real
                PQd[0] = make_float4(0.5f * S0, 0.0f, 0.5f * SM, 0.0f);
                v2f Z4 = sbuf[addr3(4096)];
                // S4096 = scale*conj(Z4); P = Q = 0.5*conj(S4096) = 0.5*scale*Z4
                float px = 0.5f * Z4.x * scale, py = 0.5f * Z4.y * scale;
                PQd[4096] = make_float4(px, py, px, py);
            } else {
                int km = 8192 - k;
                v2f Zk = sbuf[addr3(k)], Zm = sbuf[addr3(km)];
                v2f Xe = mkv2((Zk.x + Zm.x) * 0.5f, (Zk.y - Zm.y) * 0.5f);
                v2f dz = mkv2((Zk.x - Zm.x) * 0.5f, (Zk.y + Zm.y) * 0.5f);
                v2f Xo = mkv2(dz.y, -dz.x);
                v2f w = g_w81[k];                    // (cos, sin)(pi k/8192)
                v2f wXo = cmulc(Xo, w);              // Xo * (c, -s)
                v2f Sk  = (Xe + wXo) * scale;
                v2f SmC = (Xe - wXo) * scale;        // = conj(S_{M-k})
                v2f h = g_h[k];                      // ((1-s)/2, (1+s)/2) exact
                v2f Pk = Sk * h.x, Qk = SmC * h.y;
                PQd[k] = make_float4(Pk.x, Pk.y, Qk.x, Qk.y);
            }
        }
    } else {
        // transpose/pack: x(B,N,D) -> zin[(d*8+b)][n'] = x[b][2n'][d] + i x[b][2n'+1][d]
        int bid = blockIdx.x - 512;
        int nt = bid & 127, dt = (bid >> 7) & 7, bb = bid >> 10;
        float* tile = (float*)sbuf;    // [64 n][65] floats
        const float4* x4 = (const float4*)(x + ((size_t)bb * 8192 + (size_t)nt * 64) * 512 + dt * 64);
        int lane4 = tid & 15, row = tid >> 4;   // row 0..31
        #pragma unroll
        for (int r = 0; r < 2; ++r) {
            int rr = row + 32 * r;
            float4 vv = x4[(size_t)rr * 128 + lane4];
            float* dst = &tile[rr * 65 + lane4 * 4];
            dst[0] = vv.x; dst[1] = vv.y; dst[2] = vv.z; dst[3] = vv.w;
        }
        __syncthreads();
        int tx4 = tid & 15, dl = tid >> 4;      // dl 0..31
        #pragma unroll
        for (int r = 0; r < 2; ++r) {
            int dloc = dl + 32 * r;
            int d = dt * 64 + dloc;
            int npb = nt * 32 + 2 * tx4;
            float4 w;
            w.x = tile[(4 * tx4 + 0) * 65 + dloc];
            w.y = tile[(4 * tx4 + 1) * 65 + dloc];
            w.z = tile[(4 * tx4 + 2) * 65 + dloc];
            w.w = tile[(4 * tx4 + 3) * 65 + dloc];
            *(float4*)&zin[((size_t)(d * 8 + bb)) * 4096 + npb] = w;
        }
    }
}

// K2: fwd FFT -> fused packed-domain spec multiply -> inv FFT, store first half.
__global__ __launch_bounds__(512, 4) void k2_conv(const v2f* __restrict__ zin,
                                                  const float4* __restrict__ PQ,
                                                  v2f* __restrict__ yout) {
    __shared__ v2f sbuf[8192];
    int wg = blockIdx.x, tid = threadIdx.x;
    // XCD-aware swizzle: all 8 b-blocks of one d land on the same XCD (L2 reuse
    // of that d's 64KB PQ row). wg%8 selects the XCD under round-robin dispatch.
    int xcd = wg & 7, idx = wg >> 3;
    int d = (xcd << 6) | (idx >> 3), b = idx & 7;
    int io = d * 8 + b;
    const v2f* zi = zin + (size_t)io * 4096;
    const float4* PQd = PQ + (size_t)d * PQ_STRIDE;
    v2f v[16];
    #pragma unroll
    for (int n1 = 0; n1 < 8; ++n1) v[n1] = zi[(n1 << 9) + tid];
    v2f wA[15];
    #pragma unroll
    for (int j = 0; j < 15; ++j) wA[j] = g_twA[j][tid];
    // forward L1 (upper half zero)
    fft16_half<-1>(v);
    #pragma unroll
    for (int k = 1; k < 16; ++k) v[SLOT(k)] = cmul(v[SLOT(k)], wA[k - 1]);
    #pragma unroll
    for (int k1 = 0; k1 < 16; ++k1) sbuf[addr1(tid, k1)] = v[SLOT(k1)];
    __syncthreads();
    fwd_L2_L3(sbuf, tid);
    // fused unpack*spec*repack on (k, 8192-k) pairs at addr3
    #pragma unroll
    for (int tt = 0; tt < 8; ++tt) {
        int k = tid + (tt << 9);
        if (k == 0) { spec_single(sbuf, PQd, 0); spec_single(sbuf, PQd, 4096); }
        else        { spec_pair(sbuf, PQd, k); }
    }
    __syncthreads();
    inv_L3_L2(sbuf, tid);
    inv_L1(sbuf, tid, v);     // 1/8192 folded into PQ
    v2f* yo = yout + (size_t)io * 4096;
    #pragma unroll
    for (int n1 = 0; n1 < 8; ++n1) yo[(n1 << 9) + tid] = v[SLOT(n1)];
}

// K3: yout[(d*8+b)][n'] -> out[b][2n'+e][d], float4 on both global sides.
__global__ __launch_bounds__(512) void k3_unpack(const float2* __restrict__ yout,
                                                 float* __restrict__ out) {
    __shared__ float2 tile[64 * 33];   // [d-local 64][np-local 32] pad 33
    int bid = blockIdx.x;
    int nt = bid & 127, dt = (bid >> 7) & 7, bb = bid >> 10;
    int tid = threadIdx.x;
    const float4* y4 = (const float4*)yout;
    int tx4 = tid & 15, dl = tid >> 4;      // dl 0..31
    #pragma unroll
    for (int r = 0; r < 2; ++r) {
        int dloc = dl + 32 * r;
        int d = dt * 64 + dloc;
        float4 vv = y4[(size_t)(d * 8 + bb) * 2048 + nt * 16 + tx4];
        tile[dloc * 33 + 2 * tx4]     = make_float2(vv.x, vv.y);
        tile[dloc * 33 + 2 * tx4 + 1] = make_float2(vv.z, vv.w);
    }
    __syncthreads();
    const float* tf = (const float*)tile;
    int lane4 = tid & 15, nl = tid >> 4;    // nl 0..31
    #pragma unroll
    for (int r = 0; r < 2; ++r) {
        int nloc = nl + 32 * r;             // 0..63
        int npl = nloc >> 1, e = nloc & 1;
        float4 w;
        w.x = tf[((4 * lane4 + 0) * 33 + npl) * 2 + e];
        w.y = tf[((4 * lane4 + 1) * 33 + npl) * 2 + e];
        w.z = tf[((4 * lane4 + 2) * 33 + npl) * 2 + e];
        w.w = tf[((4 * lane4 + 3) * 33 + npl) * 2 + e];
        int n = nt * 64 + nloc;
        *(float4*)&out[((size_t)bb * 8192 + n) * 512 + dt * 64 + lane4 * 4] = w;
    }
}

extern "C" void kernel_launch(void* const* d_in, const int* in_sizes, int n_in,
                              void* d_out, int out_size, void* d_ws, size_t ws_size,
                              hipStream_t stream) {
    const float* x      = (const float*)d_in[0];   // (8, 8192, 512)
    const float* coeffs = (const float*)d_in[1];   // (512, 512)
    const float* dc     = (const float*)d_in[2];   // (512, 1)
    float* out = (float*)d_out;                    // (8, 8192, 512)

    float4* PQ  = (float4*)d_ws;                                   // 512*4097 f4
    v2f*    zbuf = (v2f*)((char*)d_ws + (size_t)512 * PQ_STRIDE * sizeof(float4)); // 4096*4096 c

    k_init<<<15, 512, 0, stream>>>();
    k01<<<512 + 8192, 512, 0, stream>>>(x, coeffs, dc, PQ, zbuf);
    k2_conv<<<4096, 512, 0, stream>>>(zbuf, PQ, zbuf);   // in-place per-wg
    k3_unpack<<<8192, 512, 0, stream>>>((const float2*)zbuf, out);
}